// Round 12
// baseline (359.504 us; speedup 1.0000x reference)
//
#include <hip/hip_runtime.h>
#include <hip/hip_bf16.h>

#define N_NODES 50000
#define E_EDGES 800000
#define NH 4
#define NEG_SLOPE 0.2f
#define LN_EPS 1e-5f

typedef short short8v __attribute__((ext_vector_type(8)));
typedef float f32x4  __attribute__((ext_vector_type(4)));

__device__ __forceinline__ unsigned short f2bf(float x) {
    __hip_bfloat16 h = __float2bfloat16(x);
    unsigned short u;
    __builtin_memcpy(&u, &h, sizeof(u));
    return u;
}

// ---------------------------------------------------------------------------
// CSR row_ptr from sorted dst via per-node lower_bound (no atomics).
// ---------------------------------------------------------------------------
__global__ void k_rowptr(const int* __restrict__ dst, int* __restrict__ rp) {
    int d = blockIdx.x * blockDim.x + threadIdx.x;
    if (d > N_NODES) return;
    int lo = 0, hi = E_EDGES;
    while (lo < hi) {
        int mid = (lo + hi) >> 1;
        if (dst[mid] < d) lo = mid + 1; else hi = mid;
    }
    rp[d] = lo;
}

// ---------------------------------------------------------------------------
// Weight prep: Vt[c][k] = bf16 of [W | resw][k][c]  (c in [0,320))
// ---------------------------------------------------------------------------
__global__ void k_wprep(const float* __restrict__ W0, const float* __restrict__ rw0,
                        short* __restrict__ Vt0,
                        const float* __restrict__ W1, const float* __restrict__ rw1,
                        short* __restrict__ Vt1)
{
    int idx = blockIdx.x * 256 + threadIdx.x;
    if (idx < 320 * 128) {
        int c = idx >> 7, k = idx & 127;
        float v = (c < 256) ? W0[k * 256 + c] : rw0[k * 64 + (c - 256)];
        Vt0[c * 128 + k] = (short)f2bf(v);
    }
    int i1 = idx - 320 * 128;
    if (i1 >= 0 && i1 < 320 * 64) {
        int c = i1 >> 6, k = i1 & 63;
        float v = (c < 256) ? W1[k * 256 + c] : rw1[k * 64 + (c - 256)];
        Vt1[c * 64 + k] = (short)f2bf(v);
    }
}

// ---------------------------------------------------------------------------
// MFMA node GEMM (unchanged from R11): 16 nodes x 320 cols; wave w = head w.
// ---------------------------------------------------------------------------
template<int K>
__global__ __launch_bounds__(256) void k_gemm(
    const float* __restrict__ hin, const short* __restrict__ Vt,
    const float* __restrict__ al, const float* __restrict__ ar,
    const float* __restrict__ resb,
    __hip_bfloat16* __restrict__ fs, float* __restrict__ el,
    float* __restrict__ er, float* __restrict__ resid)
{
    constexpr int KP = K + 1;
    __shared__ float hl[16 * KP];
    const int n0  = blockIdx.x * 16;
    const int t   = threadIdx.x;
    const int w   = t >> 6;
    const int l   = t & 63;
    const int c16 = l & 15;
    const int ks  = l >> 4;

    for (int idx = t; idx < 16 * K; idx += 256) {
        int n = idx / K, k = idx % K;
        hl[n * KP + k] = hin[(long long)(n0 + n) * K + k];
    }
    __syncthreads();

    constexpr int NKB = K / 32;
    f32x4 acc[5];
    #pragma unroll
    for (int i = 0; i < 5; ++i) acc[i] = (f32x4){0.f, 0.f, 0.f, 0.f};

    #pragma unroll
    for (int kb = 0; kb < NKB; ++kb) {
        const int kbase = kb * 32 + ks * 8;
        short8v af;
        #pragma unroll
        for (int j = 0; j < 8; ++j)
            af[j] = (short)f2bf(hl[c16 * KP + kbase + j]);
        #pragma unroll
        for (int i = 0; i < 4; ++i) {
            const int cg = 64 * w + 16 * i + c16;
            short8v bf = *(const short8v*)(Vt + (size_t)cg * K + kbase);
            acc[i] = __builtin_amdgcn_mfma_f32_16x16x32_bf16(af, bf, acc[i], 0, 0, 0);
        }
        {
            const int cg = 256 + 16 * w + c16;
            short8v bf = *(const short8v*)(Vt + (size_t)cg * K + kbase);
            acc[4] = __builtin_amdgcn_mfma_f32_16x16x32_bf16(af, bf, acc[4], 0, 0, 0);
        }
    }

    float el_p[4] = {0.f, 0.f, 0.f, 0.f};
    float er_p[4] = {0.f, 0.f, 0.f, 0.f};
    #pragma unroll
    for (int i = 0; i < 4; ++i) {
        const int cg = 64 * w + 16 * i + c16;
        const float alv = al[cg], arv = ar[cg];
        #pragma unroll
        for (int reg = 0; reg < 4; ++reg) {
            const float v = acc[i][reg];
            const int node = n0 + ks * 4 + reg;
            fs[(size_t)node * 256 + cg] = __float2bfloat16(v);
            el_p[reg] = fmaf(v, alv, el_p[reg]);
            er_p[reg] = fmaf(v, arv, er_p[reg]);
        }
    }
    #pragma unroll
    for (int o = 1; o < 16; o <<= 1) {
        #pragma unroll
        for (int reg = 0; reg < 4; ++reg) {
            el_p[reg] += __shfl_xor(el_p[reg], o, 64);
            er_p[reg] += __shfl_xor(er_p[reg], o, 64);
        }
    }
    if (c16 == 0) {
        #pragma unroll
        for (int reg = 0; reg < 4; ++reg) {
            const int node = n0 + ks * 4 + reg;
            el[node * NH + w] = el_p[reg];
            er[node * NH + w] = er_p[reg];
        }
    }
    {
        const int rc = 16 * w + c16;
        const float bb = resb[rc];
        #pragma unroll
        for (int reg = 0; reg < 4; ++reg) {
            const int node = n0 + ks * 4 + reg;
            resid[(size_t)node * 64 + rc] = acc[4][reg] + bb;
        }
    }
}

// ---------------------------------------------------------------------------
// TWO nodes per wave (d0, d0+1 share a CSR boundary); 8 nodes per block;
// no block barriers.  Per gather iteration: 2 independent uint4 loads
// (unroll 4 -> 8 in flight).  Epilogue duplicated via macro (static regs).
// ---------------------------------------------------------------------------
template<bool FINAL>
__global__ __launch_bounds__(256) void k_agg(
    const int* __restrict__ rp, const int* __restrict__ src,
    const unsigned int* __restrict__ fs_u,   // [N][128] uints = 256 bf16
    const float* __restrict__ el, const float* __restrict__ er,
    const float* __restrict__ resid,
    const float* __restrict__ g, const float* __restrict__ b,
    const float* __restrict__ predw, const float* __restrict__ predb,
    float* __restrict__ out)
{
    __shared__ __align__(16) float aw[8][64][4];  // per-node-slot edge weights
    __shared__ int   sjw[8][64];                  // per-node-slot edge sources
    __shared__ float ylds[8][64];                 // FINAL matvec staging

    const int t    = threadIdx.x;
    const int wv   = t >> 6;
    const int lane = t & 63;
    const int slot = wv * 2;
    const int d0   = blockIdx.x * 8 + wv * 2;     // grid = N/8, N%8==0
    const int l    = lane & 31;                   // owns cols 8l..8l+7
    const int h2   = lane >> 5;                   // half-wave id
    const int hh   = l >> 3;                      // head of owned cols

    const int e0 = rp[d0], e1 = rp[d0 + 1], e2 = rp[d0 + 2];
    const float4 erA = *(const float4*)(er + (size_t)d0 * NH);
    const float4 erB = *(const float4*)(er + (size_t)(d0 + 1) * NH);

    float4 sA = make_float4(0.f, 0.f, 0.f, 0.f);
    float4 sB = make_float4(0.f, 0.f, 0.f, 0.f);
    float accA[8], accB[8];
    #pragma unroll
    for (int i = 0; i < 8; ++i) { accA[i] = 0.f; accB[i] = 0.f; }

    int csA = e0, csB = e1;
    while (csA < e1 || csB < e2) {
        const int cntA = min(64, e1 - csA);
        const int cntB = min(64, e2 - csB);
        // stage node A weights+sources
        {
            int sj = 0;
            float4 a4 = make_float4(0.f, 0.f, 0.f, 0.f);
            if (lane < cntA) {
                sj = src[csA + lane];
                const float4 el4 = *(const float4*)(el + (size_t)sj * NH);
                float ex = el4.x + erA.x; ex = ex > 0.f ? ex : NEG_SLOPE * ex;
                float ey = el4.y + erA.y; ey = ey > 0.f ? ey : NEG_SLOPE * ey;
                float ez = el4.z + erA.z; ez = ez > 0.f ? ez : NEG_SLOPE * ez;
                float ew = el4.w + erA.w; ew = ew > 0.f ? ew : NEG_SLOPE * ew;
                a4.x = __expf(ex); a4.y = __expf(ey);
                a4.z = __expf(ez); a4.w = __expf(ew);
                sA.x += a4.x; sA.y += a4.y; sA.z += a4.z; sA.w += a4.w;
            }
            sjw[slot][lane] = sj;
            *(float4*)&aw[slot][lane][0] = a4;
        }
        // stage node B weights+sources
        {
            int sj = 0;
            float4 a4 = make_float4(0.f, 0.f, 0.f, 0.f);
            if (lane < cntB) {
                sj = src[csB + lane];
                const float4 el4 = *(const float4*)(el + (size_t)sj * NH);
                float ex = el4.x + erB.x; ex = ex > 0.f ? ex : NEG_SLOPE * ex;
                float ey = el4.y + erB.y; ey = ey > 0.f ? ey : NEG_SLOPE * ey;
                float ez = el4.z + erB.z; ez = ez > 0.f ? ez : NEG_SLOPE * ez;
                float ew = el4.w + erB.w; ew = ew > 0.f ? ew : NEG_SLOPE * ew;
                a4.x = __expf(ex); a4.y = __expf(ey);
                a4.z = __expf(ez); a4.w = __expf(ew);
                sB.x += a4.x; sB.y += a4.y; sB.z += a4.z; sB.w += a4.w;
            }
            sjw[slot + 1][lane] = sj;
            *(float4*)&aw[slot + 1][lane][0] = a4;
        }
        // fused gather: 2 independent row streams
        const int mx = max(cntA, cntB);
        #pragma unroll 4
        for (int jj = 0; jj < mx; jj += 2) {
            const int j2 = jj + h2;
            if (j2 < cntA) {
                const float w = aw[slot][j2][hh];
                const int   s = sjw[slot][j2];
                const uint4 u = *((const uint4*)(fs_u + (size_t)s * 128) + l);
                accA[0] = fmaf(w, __uint_as_float(u.x << 16),         accA[0]);
                accA[1] = fmaf(w, __uint_as_float(u.x & 0xffff0000u), accA[1]);
                accA[2] = fmaf(w, __uint_as_float(u.y << 16),         accA[2]);
                accA[3] = fmaf(w, __uint_as_float(u.y & 0xffff0000u), accA[3]);
                accA[4] = fmaf(w, __uint_as_float(u.z << 16),         accA[4]);
                accA[5] = fmaf(w, __uint_as_float(u.z & 0xffff0000u), accA[5]);
                accA[6] = fmaf(w, __uint_as_float(u.w << 16),         accA[6]);
                accA[7] = fmaf(w, __uint_as_float(u.w & 0xffff0000u), accA[7]);
            }
            if (j2 < cntB) {
                const float w = aw[slot + 1][j2][hh];
                const int   s = sjw[slot + 1][j2];
                const uint4 u = *((const uint4*)(fs_u + (size_t)s * 128) + l);
                accB[0] = fmaf(w, __uint_as_float(u.x << 16),         accB[0]);
                accB[1] = fmaf(w, __uint_as_float(u.x & 0xffff0000u), accB[1]);
                accB[2] = fmaf(w, __uint_as_float(u.y << 16),         accB[2]);
                accB[3] = fmaf(w, __uint_as_float(u.y & 0xffff0000u), accB[3]);
                accB[4] = fmaf(w, __uint_as_float(u.z << 16),         accB[4]);
                accB[5] = fmaf(w, __uint_as_float(u.z & 0xffff0000u), accB[5]);
                accB[6] = fmaf(w, __uint_as_float(u.w << 16),         accB[6]);
                accB[7] = fmaf(w, __uint_as_float(u.w & 0xffff0000u), accB[7]);
            }
        }
        csA += 64; csB += 64;
    }

    // half-wave combine + denominator reduce, both nodes
    #pragma unroll
    for (int i = 0; i < 8; ++i) {
        accA[i] += __shfl_xor(accA[i], 32);
        accB[i] += __shfl_xor(accB[i], 32);
    }
    #pragma unroll
    for (int o = 32; o > 0; o >>= 1) {
        sA.x += __shfl_xor(sA.x, o); sA.y += __shfl_xor(sA.y, o);
        sA.z += __shfl_xor(sA.z, o); sA.w += __shfl_xor(sA.w, o);
        sB.x += __shfl_xor(sB.x, o); sB.y += __shfl_xor(sB.y, o);
        sB.z += __shfl_xor(sB.z, o); sB.w += __shfl_xor(sB.w, o);
    }

#define EPILOGUE(ACC, S4, DD, SLOTN)                                          \
    {                                                                         \
        const float rsx = S4.x > 0.f ? 1.f / S4.x : 0.f;                      \
        const float rsy = S4.y > 0.f ? 1.f / S4.y : 0.f;                      \
        const float rsz = S4.z > 0.f ? 1.f / S4.z : 0.f;                      \
        const float rsw = S4.w > 0.f ? 1.f / S4.w : 0.f;                      \
        const float rsh = hh == 0 ? rsx : hh == 1 ? rsy : hh == 2 ? rsz : rsw;\
        float vv[8];                                                          \
        _Pragma("unroll")                                                     \
        for (int i = 0; i < 8; ++i) {                                         \
            float a = ACC[i] * rsh;                                           \
            a += __shfl_xor(a, 8);                                            \
            a += __shfl_xor(a, 16);                                           \
            vv[i] = a;                                                        \
        }                                                                     \
        const int c0 = 8 * (l & 7);                                           \
        const float4 r0 = *(const float4*)(resid + (size_t)(DD) * 64 + c0);   \
        const float4 r1 = *(const float4*)(resid + (size_t)(DD) * 64 + c0 + 4);\
        vv[0] = 0.25f * vv[0] + r0.x;  vv[1] = 0.25f * vv[1] + r0.y;          \
        vv[2] = 0.25f * vv[2] + r0.z;  vv[3] = 0.25f * vv[3] + r0.w;          \
        vv[4] = 0.25f * vv[4] + r1.x;  vv[5] = 0.25f * vv[5] + r1.y;          \
        vv[6] = 0.25f * vv[6] + r1.z;  vv[7] = 0.25f * vv[7] + r1.w;          \
        float p = 0.f, p2 = 0.f;                                              \
        _Pragma("unroll")                                                     \
        for (int i = 0; i < 8; ++i) { p += vv[i]; p2 += vv[i] * vv[i]; }      \
        _Pragma("unroll")                                                     \
        for (int o = 4; o > 0; o >>= 1) {                                     \
            p  += __shfl_xor(p,  o);                                          \
            p2 += __shfl_xor(p2, o);                                          \
        }                                                                     \
        const float mu  = p * (1.f / 64.f);                                   \
        const float var = p2 * (1.f / 64.f) - mu * mu;                        \
        const float inv = 1.f / sqrtf(fmaxf(var, 0.f) + LN_EPS);              \
        const float4 g0v = *(const float4*)(g + c0);                          \
        const float4 g1v = *(const float4*)(g + c0 + 4);                      \
        const float4 b0v = *(const float4*)(b + c0);                          \
        const float4 b1v = *(const float4*)(b + c0 + 4);                      \
        float y[8];                                                           \
        y[0] = fmaxf((vv[0] - mu) * inv * g0v.x + b0v.x, 0.f);                \
        y[1] = fmaxf((vv[1] - mu) * inv * g0v.y + b0v.y, 0.f);                \
        y[2] = fmaxf((vv[2] - mu) * inv * g0v.z + b0v.z, 0.f);                \
        y[3] = fmaxf((vv[3] - mu) * inv * g0v.w + b0v.w, 0.f);                \
        y[4] = fmaxf((vv[4] - mu) * inv * g1v.x + b1v.x, 0.f);                \
        y[5] = fmaxf((vv[5] - mu) * inv * g1v.y + b1v.y, 0.f);                \
        y[6] = fmaxf((vv[6] - mu) * inv * g1v.z + b1v.z, 0.f);                \
        y[7] = fmaxf((vv[7] - mu) * inv * g1v.w + b1v.w, 0.f);                \
        if (!FINAL) {                                                         \
            if (lane < 8) {                                                   \
                float4 o0 = make_float4(y[0], y[1], y[2], y[3]);              \
                float4 o1 = make_float4(y[4], y[5], y[6], y[7]);              \
                *(float4*)(out + (size_t)(DD) * 64 + 8 * lane)     = o0;      \
                *(float4*)(out + (size_t)(DD) * 64 + 8 * lane + 4) = o1;      \
            }                                                                 \
        } else {                                                              \
            if (lane < 8) {                                                   \
                _Pragma("unroll")                                             \
                for (int i = 0; i < 8; ++i) ylds[SLOTN][8 * lane + i] = y[i]; \
            }                                                                 \
            float o = predb[lane];                                            \
            _Pragma("unroll 4")                                               \
            for (int k = 0; k < 64; ++k)                                      \
                o = fmaf(ylds[SLOTN][k], predw[k * 64 + lane], o);            \
            out[(size_t)(DD) * 64 + lane] = o;                                \
        }                                                                     \
    }

    EPILOGUE(accA, sA, d0,     slot)
    EPILOGUE(accB, sB, d0 + 1, slot + 1)
#undef EPILOGUE
}

// ---------------------------------------------------------------------------
extern "C" void kernel_launch(void* const* d_in, const int* in_sizes, int n_in,
                              void* d_out, int out_size, void* d_ws, size_t ws_size,
                              hipStream_t stream)
{
    const float* feats = (const float*)d_in[0];
    const int*   src   = (const int*)  d_in[1];
    const int*   dst   = (const int*)  d_in[2];
    const float* W0    = (const float*)d_in[3];
    const float* al0   = (const float*)d_in[4];
    const float* ar0   = (const float*)d_in[5];
    const float* resw0 = (const float*)d_in[6];
    const float* resb0 = (const float*)d_in[7];
    const float* g0    = (const float*)d_in[8];
    const float* b0    = (const float*)d_in[9];
    const float* W1    = (const float*)d_in[10];
    const float* al1   = (const float*)d_in[11];
    const float* ar1   = (const float*)d_in[12];
    const float* resw1 = (const float*)d_in[13];
    const float* resb1 = (const float*)d_in[14];
    const float* g1    = (const float*)d_in[15];
    const float* b1    = (const float*)d_in[16];
    const float* predw = (const float*)d_in[17];
    const float* predb = (const float*)d_in[18];
    float* out = (float*)d_out;

    char* ws = (char*)d_ws;
    int*   rp = (int*)ws;                                   // (N+1) ints
    __hip_bfloat16* fs = (__hip_bfloat16*)(ws + 200192);    // N*256 bf16
    float* el    = (float*)((char*)fs + (size_t)N_NODES * 256 * 2);
    float* er    = el + (size_t)N_NODES * 4;
    float* resid = er + (size_t)N_NODES * 4;
    float* h1    = resid + (size_t)N_NODES * 64;
    short* Vt0   = (short*)(h1 + (size_t)N_NODES * 64);     // 320*128 bf16
    short* Vt1   = Vt0 + 320 * 128;                         // 320*64 bf16

    k_rowptr<<<(N_NODES + 1 + 255) / 256, 256, 0, stream>>>(dst, rp);
    k_wprep<<<(320 * 128 + 320 * 64 + 255) / 256, 256, 0, stream>>>(
        W0, resw0, Vt0, W1, resw1, Vt1);

    k_gemm<128><<<N_NODES / 16, 256, 0, stream>>>(
        feats, Vt0, al0, ar0, resb0, fs, el, er, resid);
    k_agg<false><<<N_NODES / 8, 256, 0, stream>>>(
        rp, src, (const unsigned int*)fs, el, er, resid, g0, b0,
        nullptr, nullptr, h1);

    k_gemm<64><<<N_NODES / 16, 256, 0, stream>>>(
        h1, Vt1, al1, ar1, resb1, fs, el, er, resid);
    k_agg<true><<<N_NODES / 8, 256, 0, stream>>>(
        rp, src, (const unsigned int*)fs, el, er, resid, g1, b1,
        predw, predb, out);
}

// Round 14
// 338.103 us; speedup vs baseline: 1.0633x; 1.0633x over previous
//
#include <hip/hip_runtime.h>
#include <hip/hip_bf16.h>

#define N_NODES 50000
#define E_EDGES 800000
#define NH 4
#define NEG_SLOPE 0.2f
#define LN_EPS 1e-5f

typedef short short8v __attribute__((ext_vector_type(8)));
typedef float f32x4  __attribute__((ext_vector_type(4)));

__device__ __forceinline__ unsigned short f2bf(float x) {
    __hip_bfloat16 h = __float2bfloat16(x);
    unsigned short u;
    __builtin_memcpy(&u, &h, sizeof(u));
    return u;
}

// ---------------------------------------------------------------------------
// CSR row_ptr from sorted dst via per-node lower_bound (no atomics).
// ---------------------------------------------------------------------------
__global__ void k_rowptr(const int* __restrict__ dst, int* __restrict__ rp) {
    int d = blockIdx.x * blockDim.x + threadIdx.x;
    if (d > N_NODES) return;
    int lo = 0, hi = E_EDGES;
    while (lo < hi) {
        int mid = (lo + hi) >> 1;
        if (dst[mid] < d) lo = mid + 1; else hi = mid;
    }
    rp[d] = lo;
}

// ---------------------------------------------------------------------------
// Weight prep: Vt[c][k] = bf16 of [W | resw][k][c]  (c in [0,320))
// ---------------------------------------------------------------------------
__global__ void k_wprep(const float* __restrict__ W0, const float* __restrict__ rw0,
                        short* __restrict__ Vt0,
                        const float* __restrict__ W1, const float* __restrict__ rw1,
                        short* __restrict__ Vt1)
{
    int idx = blockIdx.x * 256 + threadIdx.x;
    if (idx < 320 * 128) {
        int c = idx >> 7, k = idx & 127;
        float v = (c < 256) ? W0[k * 256 + c] : rw0[k * 64 + (c - 256)];
        Vt0[c * 128 + k] = (short)f2bf(v);
    }
    int i1 = idx - 320 * 128;
    if (i1 >= 0 && i1 < 320 * 64) {
        int c = i1 >> 6, k = i1 & 63;
        float v = (c < 256) ? W1[k * 256 + c] : rw1[k * 64 + (c - 256)];
        Vt1[c * 64 + k] = (short)f2bf(v);
    }
}

// ---------------------------------------------------------------------------
// Feature prep: hb0[n][k] = bf16(feats[n][k]);  8 elems/thread.
// ---------------------------------------------------------------------------
__global__ void k_hprep(const float* __restrict__ hin, unsigned int* __restrict__ hb) {
    const long long i8 = (long long)(blockIdx.x * 256 + threadIdx.x) * 8;
    if (i8 >= (long long)N_NODES * 128) return;
    const float4 a = *(const float4*)(hin + i8);
    const float4 b = *(const float4*)(hin + i8 + 4);
    uint4 pk;
    pk.x = (unsigned)f2bf(a.x) | ((unsigned)f2bf(a.y) << 16);
    pk.y = (unsigned)f2bf(a.z) | ((unsigned)f2bf(a.w) << 16);
    pk.z = (unsigned)f2bf(b.x) | ((unsigned)f2bf(b.y) << 16);
    pk.w = (unsigned)f2bf(b.z) | ((unsigned)f2bf(b.w) << 16);
    *(uint4*)(hb + (i8 >> 1)) = pk;
}

// ---------------------------------------------------------------------------
// MFMA node GEMM, A direct from global bf16 (no LDS, no barrier):
// 16 nodes x 320 cols; wave w = head w (4 fs tiles) + resid tile.
// A frag: row=lane&15 -> node n0+c16, k=(lane>>4)*8+j -> one 16B load.
// D: col=lane&15, row=(lane>>4)*4+reg  [m89-verified].
// ---------------------------------------------------------------------------
template<int K>
__global__ __launch_bounds__(256) void k_gemm(
    const short* __restrict__ hb, const short* __restrict__ Vt,
    const float* __restrict__ al, const float* __restrict__ ar,
    const float* __restrict__ resb,
    __hip_bfloat16* __restrict__ fs, float* __restrict__ el,
    float* __restrict__ er, float* __restrict__ resid)
{
    const int n0  = blockIdx.x * 16;     // 50000 % 16 == 0
    const int t   = threadIdx.x;
    const int w   = t >> 6;              // wave = head = col group
    const int l   = t & 63;
    const int c16 = l & 15;              // A-row / B,D-col within tile
    const int ks  = l >> 4;              // k-slice / D-row group

    constexpr int NKB = K / 32;
    f32x4 acc[5];
    #pragma unroll
    for (int i = 0; i < 5; ++i) acc[i] = (f32x4){0.f, 0.f, 0.f, 0.f};

    #pragma unroll
    for (int kb = 0; kb < NKB; ++kb) {
        const int kbase = kb * 32 + ks * 8;
        const short8v af = *(const short8v*)(hb + (size_t)(n0 + c16) * K + kbase);
        #pragma unroll
        for (int i = 0; i < 4; ++i) {
            const int cg = 64 * w + 16 * i + c16;
            short8v bf = *(const short8v*)(Vt + (size_t)cg * K + kbase);
            acc[i] = __builtin_amdgcn_mfma_f32_16x16x32_bf16(af, bf, acc[i], 0, 0, 0);
        }
        {
            const int cg = 256 + 16 * w + c16;
            short8v bf = *(const short8v*)(Vt + (size_t)cg * K + kbase);
            acc[4] = __builtin_amdgcn_mfma_f32_16x16x32_bf16(af, bf, acc[4], 0, 0, 0);
        }
    }

    // fs store + el/er partials
    float el_p[4] = {0.f, 0.f, 0.f, 0.f};
    float er_p[4] = {0.f, 0.f, 0.f, 0.f};
    #pragma unroll
    for (int i = 0; i < 4; ++i) {
        const int cg = 64 * w + 16 * i + c16;
        const float alv = al[cg], arv = ar[cg];
        #pragma unroll
        for (int reg = 0; reg < 4; ++reg) {
            const float v = acc[i][reg];
            const int node = n0 + ks * 4 + reg;
            fs[(size_t)node * 256 + cg] = __float2bfloat16(v);
            el_p[reg] = fmaf(v, alv, el_p[reg]);
            er_p[reg] = fmaf(v, arv, er_p[reg]);
        }
    }
    #pragma unroll
    for (int o = 1; o < 16; o <<= 1) {
        #pragma unroll
        for (int reg = 0; reg < 4; ++reg) {
            el_p[reg] += __shfl_xor(el_p[reg], o, 64);
            er_p[reg] += __shfl_xor(er_p[reg], o, 64);
        }
    }
    if (c16 == 0) {
        #pragma unroll
        for (int reg = 0; reg < 4; ++reg) {
            const int node = n0 + ks * 4 + reg;
            el[node * NH + w] = el_p[reg];
            er[node * NH + w] = er_p[reg];
        }
    }
    // resid tile
    {
        const int rc = 16 * w + c16;
        const float bb = resb[rc];
        #pragma unroll
        for (int reg = 0; reg < 4; ++reg) {
            const int node = n0 + ks * 4 + reg;
            resid[(size_t)node * 64 + rc] = acc[4][reg] + bb;
        }
    }
}

// ---------------------------------------------------------------------------
// One WAVE per destination node; 4 nodes per block; NO block barriers.
// (R11 structure — best measured: 93 µs, occ 77%.)  !FINAL writes bf16
// h1 directly (packed uint4); FINAL writes fp32 after pred-head matvec.
// ---------------------------------------------------------------------------
template<bool FINAL>
__global__ __launch_bounds__(256) void k_agg(
    const int* __restrict__ rp, const int* __restrict__ src,
    const unsigned int* __restrict__ fs_u,   // [N][128] uints = 256 bf16
    const float* __restrict__ el, const float* __restrict__ er,
    const float* __restrict__ resid,
    const float* __restrict__ g, const float* __restrict__ b,
    const float* __restrict__ predw, const float* __restrict__ predb,
    void* __restrict__ outv)
{
    __shared__ __align__(16) float aw[4][64][4];  // per-wave edge weights
    __shared__ int   sjw[4][64];                  // per-wave edge sources
    __shared__ float ylds[4][64];                 // FINAL matvec staging

    const int t    = threadIdx.x;
    const int wv   = t >> 6;
    const int lane = t & 63;
    const int d    = blockIdx.x * 4 + wv;
    const int l    = lane & 31;      // owns cols 8l..8l+7
    const int h2   = lane >> 5;      // half-wave id
    const int hh   = l >> 3;         // head of owned cols

    const int start = rp[d], end = rp[d + 1];
    const float4 er4 = *(const float4*)(er + (size_t)d * NH);

    float4 s4 = make_float4(0.f, 0.f, 0.f, 0.f);
    float acc[8];
    #pragma unroll
    for (int i = 0; i < 8; ++i) acc[i] = 0.f;

    for (int cs = start; cs < end; cs += 64) {
        const int cnt = min(64, end - cs);
        int   sj = 0;
        float4 a4 = make_float4(0.f, 0.f, 0.f, 0.f);
        if (lane < cnt) {
            sj = src[cs + lane];
            const float4 el4 = *(const float4*)(el + (size_t)sj * NH);
            float ex = el4.x + er4.x; ex = ex > 0.f ? ex : NEG_SLOPE * ex;
            float ey = el4.y + er4.y; ey = ey > 0.f ? ey : NEG_SLOPE * ey;
            float ez = el4.z + er4.z; ez = ez > 0.f ? ez : NEG_SLOPE * ez;
            float ew = el4.w + er4.w; ew = ew > 0.f ? ew : NEG_SLOPE * ew;
            a4.x = __expf(ex); a4.y = __expf(ey);
            a4.z = __expf(ez); a4.w = __expf(ew);
            s4.x += a4.x; s4.y += a4.y; s4.z += a4.z; s4.w += a4.w;
        }
        sjw[wv][lane] = sj;
        *(float4*)&aw[wv][lane][0] = a4;
        // wave-internal LDS ordering (compiler emits lgkmcnt waits)
        #pragma unroll 4
        for (int jj = 0; jj < cnt; jj += 2) {
            const int j2 = jj + h2;
            if (j2 < cnt) {
                const float w = aw[wv][j2][hh];
                const int   s = sjw[wv][j2];
                const uint4 u = *((const uint4*)(fs_u + (size_t)s * 128) + l);
                acc[0] = fmaf(w, __uint_as_float(u.x << 16),         acc[0]);
                acc[1] = fmaf(w, __uint_as_float(u.x & 0xffff0000u), acc[1]);
                acc[2] = fmaf(w, __uint_as_float(u.y << 16),         acc[2]);
                acc[3] = fmaf(w, __uint_as_float(u.y & 0xffff0000u), acc[3]);
                acc[4] = fmaf(w, __uint_as_float(u.z << 16),         acc[4]);
                acc[5] = fmaf(w, __uint_as_float(u.z & 0xffff0000u), acc[5]);
                acc[6] = fmaf(w, __uint_as_float(u.w << 16),         acc[6]);
                acc[7] = fmaf(w, __uint_as_float(u.w & 0xffff0000u), acc[7]);
            }
        }
    }

    // combine the two half-wave partials (same cols in lanes l and l+32)
    #pragma unroll
    for (int i = 0; i < 8; ++i) acc[i] += __shfl_xor(acc[i], 32);

    // reduce softmax denominators across all 64 lanes
    #pragma unroll
    for (int o = 32; o > 0; o >>= 1) {
        s4.x += __shfl_xor(s4.x, o);
        s4.y += __shfl_xor(s4.y, o);
        s4.z += __shfl_xor(s4.z, o);
        s4.w += __shfl_xor(s4.w, o);
    }
    const float rsx = s4.x > 0.f ? 1.f / s4.x : 0.f;
    const float rsy = s4.y > 0.f ? 1.f / s4.y : 0.f;
    const float rsz = s4.z > 0.f ? 1.f / s4.z : 0.f;
    const float rsw = s4.w > 0.f ? 1.f / s4.w : 0.f;
    const float rsh = hh == 0 ? rsx : hh == 1 ? rsy : hh == 2 ? rsz : rsw;
    #pragma unroll
    for (int i = 0; i < 8; ++i) acc[i] *= rsh;

    // head-mean butterfly: lanes {l, l^8, l^16, l^24} hold the 4 heads
    #pragma unroll
    for (int i = 0; i < 8; ++i) {
        acc[i] += __shfl_xor(acc[i], 8);
        acc[i] += __shfl_xor(acc[i], 16);
    }

    const int c0 = 8 * (l & 7);
    const float4 r0 = *(const float4*)(resid + (size_t)d * 64 + c0);
    const float4 r1 = *(const float4*)(resid + (size_t)d * 64 + c0 + 4);
    float v[8];
    v[0] = 0.25f * acc[0] + r0.x;  v[1] = 0.25f * acc[1] + r0.y;
    v[2] = 0.25f * acc[2] + r0.z;  v[3] = 0.25f * acc[3] + r0.w;
    v[4] = 0.25f * acc[4] + r1.x;  v[5] = 0.25f * acc[5] + r1.y;
    v[6] = 0.25f * acc[6] + r1.z;  v[7] = 0.25f * acc[7] + r1.w;

    // LayerNorm stats over the 64 cols (8 families × 8 regs)
    float p = 0.f, p2 = 0.f;
    #pragma unroll
    for (int i = 0; i < 8; ++i) { p += v[i]; p2 += v[i] * v[i]; }
    #pragma unroll
    for (int o = 4; o > 0; o >>= 1) {
        p  += __shfl_xor(p,  o);
        p2 += __shfl_xor(p2, o);
    }
    const float mu  = p * (1.f / 64.f);
    const float var = p2 * (1.f / 64.f) - mu * mu;
    const float inv = 1.f / sqrtf(fmaxf(var, 0.f) + LN_EPS);

    const float4 g0v = *(const float4*)(g + c0);
    const float4 g1v = *(const float4*)(g + c0 + 4);
    const float4 b0v = *(const float4*)(b + c0);
    const float4 b1v = *(const float4*)(b + c0 + 4);
    float y[8];
    y[0] = fmaxf((v[0] - mu) * inv * g0v.x + b0v.x, 0.f);
    y[1] = fmaxf((v[1] - mu) * inv * g0v.y + b0v.y, 0.f);
    y[2] = fmaxf((v[2] - mu) * inv * g0v.z + b0v.z, 0.f);
    y[3] = fmaxf((v[3] - mu) * inv * g0v.w + b0v.w, 0.f);
    y[4] = fmaxf((v[4] - mu) * inv * g1v.x + b1v.x, 0.f);
    y[5] = fmaxf((v[5] - mu) * inv * g1v.y + b1v.y, 0.f);
    y[6] = fmaxf((v[6] - mu) * inv * g1v.z + b1v.z, 0.f);
    y[7] = fmaxf((v[7] - mu) * inv * g1v.w + b1v.w, 0.f);

    if (!FINAL) {
        // write h1 as bf16 directly (A-operand of layer-1 MFMA GEMM)
        if (lane < 8) {
            unsigned int* hb1 = (unsigned int*)outv;
            uint4 pk;
            pk.x = (unsigned)f2bf(y[0]) | ((unsigned)f2bf(y[1]) << 16);
            pk.y = (unsigned)f2bf(y[2]) | ((unsigned)f2bf(y[3]) << 16);
            pk.z = (unsigned)f2bf(y[4]) | ((unsigned)f2bf(y[5]) << 16);
            pk.w = (unsigned)f2bf(y[6]) | ((unsigned)f2bf(y[7]) << 16);
            *(uint4*)(hb1 + (size_t)d * 32 + 4 * lane) = pk;
        }
    } else {
        float* out = (float*)outv;
        if (lane < 8) {
            #pragma unroll
            for (int i = 0; i < 8; ++i) ylds[wv][8 * lane + i] = y[i];
        }
        // wave-internal LDS ordering; then 64-lane matvec: lane = out col
        float o = predb[lane];
        #pragma unroll 4
        for (int k = 0; k < 64; ++k)
            o = fmaf(ylds[wv][k], predw[k * 64 + lane], o);
        out[(size_t)d * 64 + lane] = o;
    }
}

// ---------------------------------------------------------------------------
extern "C" void kernel_launch(void* const* d_in, const int* in_sizes, int n_in,
                              void* d_out, int out_size, void* d_ws, size_t ws_size,
                              hipStream_t stream)
{
    const float* feats = (const float*)d_in[0];
    const int*   src   = (const int*)  d_in[1];
    const int*   dst   = (const int*)  d_in[2];
    const float* W0    = (const float*)d_in[3];
    const float* al0   = (const float*)d_in[4];
    const float* ar0   = (const float*)d_in[5];
    const float* resw0 = (const float*)d_in[6];
    const float* resb0 = (const float*)d_in[7];
    const float* g0    = (const float*)d_in[8];
    const float* b0    = (const float*)d_in[9];
    const float* W1    = (const float*)d_in[10];
    const float* al1   = (const float*)d_in[11];
    const float* ar1   = (const float*)d_in[12];
    const float* resw1 = (const float*)d_in[13];
    const float* resb1 = (const float*)d_in[14];
    const float* g1    = (const float*)d_in[15];
    const float* b1    = (const float*)d_in[16];
    const float* predw = (const float*)d_in[17];
    const float* predb = (const float*)d_in[18];
    float* out = (float*)d_out;

    char* ws = (char*)d_ws;
    int*   rp = (int*)ws;                                   // (N+1) ints
    __hip_bfloat16* fs = (__hip_bfloat16*)(ws + 200192);    // N*256 bf16
    float* el    = (float*)((char*)fs + (size_t)N_NODES * 256 * 2);
    float* er    = el + (size_t)N_NODES * 4;
    float* resid = er + (size_t)N_NODES * 4;
    short* hb0   = (short*)(resid + (size_t)N_NODES * 64);  // N*128 bf16
    short* hb1   = hb0 + (size_t)N_NODES * 128;             // N*64 bf16
    short* Vt0   = hb1 + (size_t)N_NODES * 64;              // 320*128 bf16
    short* Vt1   = Vt0 + 320 * 128;                         // 320*64 bf16

    k_rowptr<<<(N_NODES + 1 + 255) / 256, 256, 0, stream>>>(dst, rp);
    k_wprep<<<(320 * 128 + 320 * 64 + 255) / 256, 256, 0, stream>>>(
        W0, resw0, Vt0, W1, resw1, Vt1);
    k_hprep<<<(N_NODES * 128 / 8 + 255) / 256, 256, 0, stream>>>(
        feats, (unsigned int*)hb0);

    k_gemm<128><<<N_NODES / 16, 256, 0, stream>>>(
        hb0, Vt0, al0, ar0, resb0, fs, el, er, resid);
    k_agg<false><<<N_NODES / 4, 256, 0, stream>>>(
        rp, src, (const unsigned int*)fs, el, er, resid, g0, b0,
        nullptr, nullptr, hb1);

    k_gemm<64><<<N_NODES / 16, 256, 0, stream>>>(
        hb1, Vt1, al1, ar1, resb1, fs, el, er, resid);
    k_agg<true><<<N_NODES / 4, 256, 0, stream>>>(
        rp, src, (const unsigned int*)fs, el, er, resid, g1, b1,
        predw, predb, out);
}

// Round 15
// 322.110 us; speedup vs baseline: 1.1161x; 1.0497x over previous
//
#include <hip/hip_runtime.h>
#include <hip/hip_bf16.h>

#define N_NODES 50000
#define E_EDGES 800000
#define NH 4
#define NEG_SLOPE 0.2f
#define LN_EPS 1e-5f

typedef short short8v __attribute__((ext_vector_type(8)));
typedef float f32x4  __attribute__((ext_vector_type(4)));

__device__ __forceinline__ unsigned short f2bf(float x) {
    __hip_bfloat16 h = __float2bfloat16(x);
    unsigned short u;
    __builtin_memcpy(&u, &h, sizeof(u));
    return u;
}

// ---------------------------------------------------------------------------
// Fused prep: CSR row_ptr (idx <= N) + weight transpose/convert
// Vt[c][k] = bf16([W|resw][k][c]).  Grid covers 61440 threads.
// ---------------------------------------------------------------------------
__global__ void k_prep(const int* __restrict__ dst, int* __restrict__ rp,
                       const float* __restrict__ W0, const float* __restrict__ rw0,
                       short* __restrict__ Vt0,
                       const float* __restrict__ W1, const float* __restrict__ rw1,
                       short* __restrict__ Vt1)
{
    const int idx = blockIdx.x * 256 + threadIdx.x;
    if (idx <= N_NODES) {
        int lo = 0, hi = E_EDGES;
        while (lo < hi) {
            int mid = (lo + hi) >> 1;
            if (dst[mid] < idx) lo = mid + 1; else hi = mid;
        }
        rp[idx] = lo;
    }
    if (idx < 320 * 128) {
        int c = idx >> 7, k = idx & 127;
        float v = (c < 256) ? W0[k * 256 + c] : rw0[k * 64 + (c - 256)];
        Vt0[c * 128 + k] = (short)f2bf(v);
    } else if (idx < 320 * 128 + 320 * 64) {
        int i1 = idx - 320 * 128;
        int c = i1 >> 6, k = i1 & 63;
        float v = (c < 256) ? W1[k * 256 + c] : rw1[k * 64 + (c - 256)];
        Vt1[c * 64 + k] = (short)f2bf(v);
    }
}

// ---------------------------------------------------------------------------
// MFMA node GEMM, 32 nodes/block (2 A-tiles), A direct from global
// (fp32 feats when AF32, else bf16), no LDS, no barrier.
// Wave w = head w: 4 fs col-tiles + 1 resid tile, x2 node-tiles = 10 MFMA/kb.
// A frag: row=lane&15 -> node n0+16a+c16, k=(lane>>4)*8+j (one/two 16B loads).
// D: col=lane&15, row=(lane>>4)*4+reg  [m89-verified].
// Tail block (50000 = 32*1562+16): clamp loads, guard stores.
// ---------------------------------------------------------------------------
template<int K, bool AF32>
__global__ __launch_bounds__(256) void k_gemm(
    const void* __restrict__ hA, const short* __restrict__ Vt,
    const float* __restrict__ al, const float* __restrict__ ar,
    const float* __restrict__ resb,
    __hip_bfloat16* __restrict__ fs, float* __restrict__ el,
    float* __restrict__ er, float* __restrict__ resid)
{
    const int n0  = blockIdx.x * 32;
    const int t   = threadIdx.x;
    const int w   = t >> 6;              // wave = head = col group
    const int l   = t & 63;
    const int c16 = l & 15;              // A-row / B,D-col within tile
    const int ks  = l >> 4;              // k-slice / D-row group

    constexpr int NKB = K / 32;
    f32x4 acc[2][5];
    #pragma unroll
    for (int a = 0; a < 2; ++a)
        #pragma unroll
        for (int i = 0; i < 5; ++i) acc[a][i] = (f32x4){0.f, 0.f, 0.f, 0.f};

    #pragma unroll
    for (int kb = 0; kb < NKB; ++kb) {
        const int kbase = kb * 32 + ks * 8;
        short8v af[2];
        #pragma unroll
        for (int a = 0; a < 2; ++a) {
            const int rowc = min(n0 + 16 * a + c16, N_NODES - 1);
            if (AF32) {
                const float* hf = (const float*)hA;
                const float4 x = *(const float4*)(hf + (size_t)rowc * K + kbase);
                const float4 y = *(const float4*)(hf + (size_t)rowc * K + kbase + 4);
                af[a][0] = (short)f2bf(x.x); af[a][1] = (short)f2bf(x.y);
                af[a][2] = (short)f2bf(x.z); af[a][3] = (short)f2bf(x.w);
                af[a][4] = (short)f2bf(y.x); af[a][5] = (short)f2bf(y.y);
                af[a][6] = (short)f2bf(y.z); af[a][7] = (short)f2bf(y.w);
            } else {
                const short* hs = (const short*)hA;
                af[a] = *(const short8v*)(hs + (size_t)rowc * K + kbase);
            }
        }
        #pragma unroll
        for (int i = 0; i < 5; ++i) {
            const int cg = (i < 4) ? (64 * w + 16 * i + c16) : (256 + 16 * w + c16);
            const short8v bf = *(const short8v*)(Vt + (size_t)cg * K + kbase);
            acc[0][i] = __builtin_amdgcn_mfma_f32_16x16x32_bf16(af[0], bf, acc[0][i], 0, 0, 0);
            acc[1][i] = __builtin_amdgcn_mfma_f32_16x16x32_bf16(af[1], bf, acc[1][i], 0, 0, 0);
        }
    }

    // epilogue per node-tile
    #pragma unroll
    for (int a = 0; a < 2; ++a) {
        float el_p[4] = {0.f, 0.f, 0.f, 0.f};
        float er_p[4] = {0.f, 0.f, 0.f, 0.f};
        #pragma unroll
        for (int i = 0; i < 4; ++i) {
            const int cg = 64 * w + 16 * i + c16;
            const float alv = al[cg], arv = ar[cg];
            #pragma unroll
            for (int reg = 0; reg < 4; ++reg) {
                const float v = acc[a][i][reg];
                const int node = n0 + 16 * a + ks * 4 + reg;
                if (node < N_NODES)
                    fs[(size_t)node * 256 + cg] = __float2bfloat16(v);
                el_p[reg] = fmaf(v, alv, el_p[reg]);
                er_p[reg] = fmaf(v, arv, er_p[reg]);
            }
        }
        #pragma unroll
        for (int o = 1; o < 16; o <<= 1) {
            #pragma unroll
            for (int reg = 0; reg < 4; ++reg) {
                el_p[reg] += __shfl_xor(el_p[reg], o, 64);
                er_p[reg] += __shfl_xor(er_p[reg], o, 64);
            }
        }
        if (c16 == 0) {
            #pragma unroll
            for (int reg = 0; reg < 4; ++reg) {
                const int node = n0 + 16 * a + ks * 4 + reg;
                if (node < N_NODES) {
                    el[node * NH + w] = el_p[reg];
                    er[node * NH + w] = er_p[reg];
                }
            }
        }
        {
            const int rc = 16 * w + c16;
            const float bb = resb[rc];
            #pragma unroll
            for (int reg = 0; reg < 4; ++reg) {
                const int node = n0 + 16 * a + ks * 4 + reg;
                if (node < N_NODES)
                    resid[(size_t)node * 64 + rc] = acc[a][4][reg] + bb;
            }
        }
    }
}

// ---------------------------------------------------------------------------
// One WAVE per destination node; 4 nodes per block; NO block barriers.
// (best measured structure: 92 µs, occ 76%.)  !FINAL writes bf16 h1
// directly (packed uint4); FINAL writes fp32 after pred-head matvec.
// ---------------------------------------------------------------------------
template<bool FINAL>
__global__ __launch_bounds__(256) void k_agg(
    const int* __restrict__ rp, const int* __restrict__ src,
    const unsigned int* __restrict__ fs_u,   // [N][128] uints = 256 bf16
    const float* __restrict__ el, const float* __restrict__ er,
    const float* __restrict__ resid,
    const float* __restrict__ g, const float* __restrict__ b,
    const float* __restrict__ predw, const float* __restrict__ predb,
    void* __restrict__ outv)
{
    __shared__ __align__(16) float aw[4][64][4];  // per-wave edge weights
    __shared__ int   sjw[4][64];                  // per-wave edge sources
    __shared__ float ylds[4][64];                 // FINAL matvec staging

    const int t    = threadIdx.x;
    const int wv   = t >> 6;
    const int lane = t & 63;
    const int d    = blockIdx.x * 4 + wv;
    const int l    = lane & 31;      // owns cols 8l..8l+7
    const int h2   = lane >> 5;      // half-wave id
    const int hh   = l >> 3;         // head of owned cols

    const int start = rp[d], end = rp[d + 1];
    const float4 er4 = *(const float4*)(er + (size_t)d * NH);

    float4 s4 = make_float4(0.f, 0.f, 0.f, 0.f);
    float acc[8];
    #pragma unroll
    for (int i = 0; i < 8; ++i) acc[i] = 0.f;

    for (int cs = start; cs < end; cs += 64) {
        const int cnt = min(64, end - cs);
        int   sj = 0;
        float4 a4 = make_float4(0.f, 0.f, 0.f, 0.f);
        if (lane < cnt) {
            sj = src[cs + lane];
            const float4 el4 = *(const float4*)(el + (size_t)sj * NH);
            float ex = el4.x + er4.x; ex = ex > 0.f ? ex : NEG_SLOPE * ex;
            float ey = el4.y + er4.y; ey = ey > 0.f ? ey : NEG_SLOPE * ey;
            float ez = el4.z + er4.z; ez = ez > 0.f ? ez : NEG_SLOPE * ez;
            float ew = el4.w + er4.w; ew = ew > 0.f ? ew : NEG_SLOPE * ew;
            a4.x = __expf(ex); a4.y = __expf(ey);
            a4.z = __expf(ez); a4.w = __expf(ew);
            s4.x += a4.x; s4.y += a4.y; s4.z += a4.z; s4.w += a4.w;
        }
        sjw[wv][lane] = sj;
        *(float4*)&aw[wv][lane][0] = a4;
        // wave-internal LDS ordering (compiler emits lgkmcnt waits)
        #pragma unroll 4
        for (int jj = 0; jj < cnt; jj += 2) {
            const int j2 = jj + h2;
            if (j2 < cnt) {
                const float w = aw[wv][j2][hh];
                const int   s = sjw[wv][j2];
                const uint4 u = *((const uint4*)(fs_u + (size_t)s * 128) + l);
                acc[0] = fmaf(w, __uint_as_float(u.x << 16),         acc[0]);
                acc[1] = fmaf(w, __uint_as_float(u.x & 0xffff0000u), acc[1]);
                acc[2] = fmaf(w, __uint_as_float(u.y << 16),         acc[2]);
                acc[3] = fmaf(w, __uint_as_float(u.y & 0xffff0000u), acc[3]);
                acc[4] = fmaf(w, __uint_as_float(u.z << 16),         acc[4]);
                acc[5] = fmaf(w, __uint_as_float(u.z & 0xffff0000u), acc[5]);
                acc[6] = fmaf(w, __uint_as_float(u.w << 16),         acc[6]);
                acc[7] = fmaf(w, __uint_as_float(u.w & 0xffff0000u), acc[7]);
            }
        }
    }

    // combine the two half-wave partials (same cols in lanes l and l+32)
    #pragma unroll
    for (int i = 0; i < 8; ++i) acc[i] += __shfl_xor(acc[i], 32);

    // reduce softmax denominators across all 64 lanes
    #pragma unroll
    for (int o = 32; o > 0; o >>= 1) {
        s4.x += __shfl_xor(s4.x, o);
        s4.y += __shfl_xor(s4.y, o);
        s4.z += __shfl_xor(s4.z, o);
        s4.w += __shfl_xor(s4.w, o);
    }
    const float rsx = s4.x > 0.f ? 1.f / s4.x : 0.f;
    const float rsy = s4.y > 0.f ? 1.f / s4.y : 0.f;
    const float rsz = s4.z > 0.f ? 1.f / s4.z : 0.f;
    const float rsw = s4.w > 0.f ? 1.f / s4.w : 0.f;
    const float rsh = hh == 0 ? rsx : hh == 1 ? rsy : hh == 2 ? rsz : rsw;
    #pragma unroll
    for (int i = 0; i < 8; ++i) acc[i] *= rsh;

    // head-mean butterfly: lanes {l, l^8, l^16, l^24} hold the 4 heads
    #pragma unroll
    for (int i = 0; i < 8; ++i) {
        acc[i] += __shfl_xor(acc[i], 8);
        acc[i] += __shfl_xor(acc[i], 16);
    }

    const int c0 = 8 * (l & 7);
    const float4 r0 = *(const float4*)(resid + (size_t)d * 64 + c0);
    const float4 r1 = *(const float4*)(resid + (size_t)d * 64 + c0 + 4);
    float v[8];
    v[0] = 0.25f * acc[0] + r0.x;  v[1] = 0.25f * acc[1] + r0.y;
    v[2] = 0.25f * acc[2] + r0.z;  v[3] = 0.25f * acc[3] + r0.w;
    v[4] = 0.25f * acc[4] + r1.x;  v[5] = 0.25f * acc[5] + r1.y;
    v[6] = 0.25f * acc[6] + r1.z;  v[7] = 0.25f * acc[7] + r1.w;

    // LayerNorm stats over the 64 cols (8 families × 8 regs)
    float p = 0.f, p2 = 0.f;
    #pragma unroll
    for (int i = 0; i < 8; ++i) { p += v[i]; p2 += v[i] * v[i]; }
    #pragma unroll
    for (int o = 4; o > 0; o >>= 1) {
        p  += __shfl_xor(p,  o);
        p2 += __shfl_xor(p2, o);
    }
    const float mu  = p * (1.f / 64.f);
    const float var = p2 * (1.f / 64.f) - mu * mu;
    const float inv = 1.f / sqrtf(fmaxf(var, 0.f) + LN_EPS);

    const float4 g0v = *(const float4*)(g + c0);
    const float4 g1v = *(const float4*)(g + c0 + 4);
    const float4 b0v = *(const float4*)(b + c0);
    const float4 b1v = *(const float4*)(b + c0 + 4);
    float y[8];
    y[0] = fmaxf((v[0] - mu) * inv * g0v.x + b0v.x, 0.f);
    y[1] = fmaxf((v[1] - mu) * inv * g0v.y + b0v.y, 0.f);
    y[2] = fmaxf((v[2] - mu) * inv * g0v.z + b0v.z, 0.f);
    y[3] = fmaxf((v[3] - mu) * inv * g0v.w + b0v.w, 0.f);
    y[4] = fmaxf((v[4] - mu) * inv * g1v.x + b1v.x, 0.f);
    y[5] = fmaxf((v[5] - mu) * inv * g1v.y + b1v.y, 0.f);
    y[6] = fmaxf((v[6] - mu) * inv * g1v.z + b1v.z, 0.f);
    y[7] = fmaxf((v[7] - mu) * inv * g1v.w + b1v.w, 0.f);

    if (!FINAL) {
        // write h1 as bf16 directly (A-operand of layer-1 MFMA GEMM)
        if (lane < 8) {
            unsigned int* hb1 = (unsigned int*)outv;
            uint4 pk;
            pk.x = (unsigned)f2bf(y[0]) | ((unsigned)f2bf(y[1]) << 16);
            pk.y = (unsigned)f2bf(y[2]) | ((unsigned)f2bf(y[3]) << 16);
            pk.z = (unsigned)f2bf(y[4]) | ((unsigned)f2bf(y[5]) << 16);
            pk.w = (unsigned)f2bf(y[6]) | ((unsigned)f2bf(y[7]) << 16);
            *(uint4*)(hb1 + (size_t)d * 32 + 4 * lane) = pk;
        }
    } else {
        float* out = (float*)outv;
        if (lane < 8) {
            #pragma unroll
            for (int i = 0; i < 8; ++i) ylds[wv][8 * lane + i] = y[i];
        }
        // wave-internal LDS ordering; then 64-lane matvec: lane = out col
        float o = predb[lane];
        #pragma unroll 4
        for (int k = 0; k < 64; ++k)
            o = fmaf(ylds[wv][k], predw[k * 64 + lane], o);
        out[(size_t)d * 64 + lane] = o;
    }
}

// ---------------------------------------------------------------------------
extern "C" void kernel_launch(void* const* d_in, const int* in_sizes, int n_in,
                              void* d_out, int out_size, void* d_ws, size_t ws_size,
                              hipStream_t stream)
{
    const float* feats = (const float*)d_in[0];
    const int*   src   = (const int*)  d_in[1];
    const int*   dst   = (const int*)  d_in[2];
    const float* W0    = (const float*)d_in[3];
    const float* al0   = (const float*)d_in[4];
    const float* ar0   = (const float*)d_in[5];
    const float* resw0 = (const float*)d_in[6];
    const float* resb0 = (const float*)d_in[7];
    const float* g0    = (const float*)d_in[8];
    const float* b0    = (const float*)d_in[9];
    const float* W1    = (const float*)d_in[10];
    const float* al1   = (const float*)d_in[11];
    const float* ar1   = (const float*)d_in[12];
    const float* resw1 = (const float*)d_in[13];
    const float* resb1 = (const float*)d_in[14];
    const float* g1    = (const float*)d_in[15];
    const float* b1    = (const float*)d_in[16];
    const float* predw = (const float*)d_in[17];
    const float* predb = (const float*)d_in[18];
    float* out = (float*)d_out;

    char* ws = (char*)d_ws;
    int*   rp = (int*)ws;                                   // (N+1) ints
    __hip_bfloat16* fs = (__hip_bfloat16*)(ws + 200192);    // N*256 bf16
    float* el    = (float*)((char*)fs + (size_t)N_NODES * 256 * 2);
    float* er    = el + (size_t)N_NODES * 4;
    float* resid = er + (size_t)N_NODES * 4;
    short* hb1   = (short*)(resid + (size_t)N_NODES * 64);  // N*64 bf16
    short* Vt0   = hb1 + (size_t)N_NODES * 64;              // 320*128 bf16
    short* Vt1   = Vt0 + 320 * 128;                         // 320*64 bf16

    k_prep<<<240, 256, 0, stream>>>(dst, rp, W0, resw0, Vt0, W1, resw1, Vt1);

    k_gemm<128, true><<<(N_NODES + 31) / 32, 256, 0, stream>>>(
        feats, Vt0, al0, ar0, resb0, fs, el, er, resid);
    k_agg<false><<<N_NODES / 4, 256, 0, stream>>>(
        rp, src, (const unsigned int*)fs, el, er, resid, g0, b0,
        nullptr, nullptr, hb1);

    k_gemm<64, false><<<(N_NODES + 31) / 32, 256, 0, stream>>>(
        hb1, Vt1, al1, ar1, resb1, fs, el, er, resid);
    k_agg<true><<<N_NODES / 4, 256, 0, stream>>>(
        rp, src, (const unsigned int*)fs, el, er, resid, g1, b1,
        predw, predb, out);
}